// Round 12
// baseline (930.282 us; speedup 1.0000x reference)
//
#include <hip/hip_runtime.h>
#include <hip/hip_bf16.h>

#define Nn 16384
#define Dd 256
#define L2E 1.4426950408889634f
#define LN2 0.6931471805599453f

typedef __attribute__((ext_vector_type(8))) int int8v;
typedef __attribute__((ext_vector_type(16))) float f32x16;

__device__ inline void gload_lds16(const void* g, void* l) {
    __builtin_amdgcn_global_load_lds(
        (const __attribute__((address_space(1))) void*)g,
        (__attribute__((address_space(3))) void*)l, 16, 0, 0);
}

// fp32 -> fp8 e4m3 (HW RNE). A pre-scaled by log2e: epilogue softplus works in
// exp2/log2 domain with no per-element muls.
__global__ __launch_bounds__(256) void cvt_kernel(
        const float4* __restrict__ a, const float4* __restrict__ b,
        int2* __restrict__ oa, int2* __restrict__ ob) {
    int i = blockIdx.x * 256 + threadIdx.x;
    float4 a0 = a[2 * i], a1 = a[2 * i + 1];
    float4 b0 = b[2 * i], b1 = b[2 * i + 1];
    int alo = __builtin_amdgcn_cvt_pk_fp8_f32(a0.x * L2E, a0.y * L2E, 0, false);
    alo     = __builtin_amdgcn_cvt_pk_fp8_f32(a0.z * L2E, a0.w * L2E, alo, true);
    int ahi = __builtin_amdgcn_cvt_pk_fp8_f32(a1.x * L2E, a1.y * L2E, 0, false);
    ahi     = __builtin_amdgcn_cvt_pk_fp8_f32(a1.z * L2E, a1.w * L2E, ahi, true);
    int blo = __builtin_amdgcn_cvt_pk_fp8_f32(b0.x, b0.y, 0, false);
    blo     = __builtin_amdgcn_cvt_pk_fp8_f32(b0.z, b0.w, blo, true);
    int bhi = __builtin_amdgcn_cvt_pk_fp8_f32(b1.x, b1.y, 0, false);
    bhi     = __builtin_amdgcn_cvt_pk_fp8_f32(b1.z, b1.w, bhi, true);
    oa[i] = make_int2(alo, ahi);
    ob[i] = make_int2(blo, bhi);
}

// 2x ds_read_b128 of one lane's 32 contiguous K-bytes from a [rows][256B]
// full-K LDS tile, XOR-deswizzled (16 chunks/row, chunk ^= row&15).
// Measured ZERO bank conflicts (R8/R9/R10).
__device__ inline int8v read_frag256(const unsigned char* base, int rr, int cb) {
    int x = rr & 15;
    int4 lo = *(const int4*)&base[rr * 256 + ((cb ^ x) * 16)];
    int4 hi = *(const int4*)&base[rr * 256 + (((cb + 1) ^ x) * 16)];
    int8v r;
    r[0] = lo.x; r[1] = lo.y; r[2] = lo.z; r[3] = lo.w;
    r[4] = hi.x; r[5] = hi.y; r[6] = hi.z; r[7] = hi.w;
    return r;
}

// Fused MX-fp8 GEMM (sim' = log2e * za.zb^T, unit e8m0 scales) + siglip loss.
// R10's straight-line block extended to TWO B-panels, software-pipelined with
// counted vmcnt (no loop — R8/R9 spills were loop-carried acc liveness):
//   issue stage A(8) B1(4) B2(4) -> vmcnt(4)=A+B1 landed -> MFMA1+epilogue1
//   (B2's flight hidden under them) -> vmcnt(0) -> MFMA2+epilogue2.
// A staged once, amortized over 256 output cols. Tile 256(M)x256(N, 2x128),
// full K=256. LDS 64+32+32=128KB. 512 thr = 8 waves (4M x 2N per panel),
// wave tile 64x64 -> acc[2][2] reused sequentially (R10's no-spill shape).
__global__ __launch_bounds__(512, 2) void siglip_kernel(
        const unsigned char* __restrict__ ga,   // za*log2e fp8 [16384][256]
        const unsigned char* __restrict__ gb,   // zb fp8 [16384][256]
        const float* __restrict__ bp,           // bias scalar
        float* __restrict__ out) {
    __shared__ unsigned char As[256 * 256];    // 64 KB, full-K A tile
    __shared__ unsigned char Bs1[128 * 256];   // 32 KB, full-K B panel 1
    __shared__ unsigned char Bs2[128 * 256];   // 32 KB, full-K B panel 2
    __shared__ float wsum[8];

    const int tid  = threadIdx.x;
    const int lane = tid & 63;
    const int wid  = tid >> 6;
    const int wm   = wid >> 1;     // 0..3 -> 64-row slice of the 256-row tile
    const int wn   = wid & 1;      // 0..1 -> 64-col slice of a 128-col panel
    const int l31  = lane & 31;
    const int h    = lane >> 5;

    // XCD-chunked swizzle + 8x8 supertile (grid 4096 = 8 XCD x 512).
    const int bid = blockIdx.x;
    const int nid = (bid & 7) * 512 + (bid >> 3);
    const int sc  = nid >> 6, sl = nid & 63;
    const int by  = (sc >> 3) * 8 + (sl >> 3);   // 0..63 (M/256)
    const int bx  = (sc & 7) * 8 + (sl & 7);     // 0..63 (N/256)
    const size_t rowA0 = (size_t)by * 256;
    const size_t rowB0 = (size_t)bx * 256;

    const float b2 = bp[0] * L2E;

    // ---- issue ALL staging upfront: A(8/thr), B1(4/thr), B2(4/thr) ----
    // source chunk pre-swizzled ((c&15)^(row&15)) -> conflict-free reads.
#pragma unroll
    for (int p = 0; p < 8; ++p) {
        int c = p * 512 + tid; int row = c >> 4;
        int scl = (c & 15) ^ (row & 15);
        gload_lds16(&ga[(rowA0 + row) * Dd + scl * 16], &As[c * 16]);
    }
#pragma unroll
    for (int p = 0; p < 4; ++p) {
        int c = p * 512 + tid; int row = c >> 4;
        int scl = (c & 15) ^ (row & 15);
        gload_lds16(&gb[(rowB0 + row) * Dd + scl * 16], &Bs1[c * 16]);
    }
#pragma unroll
    for (int p = 0; p < 4; ++p) {
        int c = p * 512 + tid; int row = c >> 4;
        int scl = (c & 15) ^ (row & 15);
        gload_lds16(&gb[(rowB0 + 128 + row) * Dd + scl * 16], &Bs2[c * 16]);
    }

    float r1 = 0.f, r2 = 0.f, ld = 0.f;
    const int diag = (bx == by);

    // ================= panel 1 =================
    f32x16 acc[2][2];
#pragma unroll
    for (int mf = 0; mf < 2; ++mf)
#pragma unroll
        for (int nf = 0; nf < 2; ++nf)
#pragma unroll
            for (int q = 0; q < 16; ++q) acc[mf][nf][q] = -b2;

    // wait A+B1 landed; B2's 4 loads stay in flight (hidden under panel 1)
    asm volatile("s_waitcnt vmcnt(4)" ::: "memory");
    __builtin_amdgcn_s_barrier();
    asm volatile("" ::: "memory");

#pragma unroll
    for (int s = 0; s < 4; ++s) {
        int cb = s * 4 + h * 2;
        int8v aF0 = read_frag256(As, wm * 64 + l31, cb);
        int8v aF1 = read_frag256(As, wm * 64 + 32 + l31, cb);
        int8v bF0 = read_frag256(Bs1, wn * 64 + l31, cb);
        int8v bF1 = read_frag256(Bs1, wn * 64 + 32 + l31, cb);
        acc[0][0] = __builtin_amdgcn_mfma_scale_f32_32x32x64_f8f6f4(
            aF0, bF0, acc[0][0], 0, 0, 0, 0x7F7F7F7F, 0, 0x7F7F7F7F);
        acc[0][1] = __builtin_amdgcn_mfma_scale_f32_32x32x64_f8f6f4(
            aF0, bF1, acc[0][1], 0, 0, 0, 0x7F7F7F7F, 0, 0x7F7F7F7F);
        acc[1][0] = __builtin_amdgcn_mfma_scale_f32_32x32x64_f8f6f4(
            aF1, bF0, acc[1][0], 0, 0, 0, 0x7F7F7F7F, 0, 0x7F7F7F7F);
        acc[1][1] = __builtin_amdgcn_mfma_scale_f32_32x32x64_f8f6f4(
            aF1, bF1, acc[1][1], 0, 0, 0, 0x7F7F7F7F, 0, 0x7F7F7F7F);
    }

    // epilogue 1 (pure VALU/trans; B2 lands underneath)
#pragma unroll
    for (int mf = 0; mf < 2; ++mf)
#pragma unroll
        for (int nf = 0; nf < 2; ++nf)
#pragma unroll
            for (int q = 0; q < 16; ++q) {
                float y = acc[mf][nf][q];
                r1 += fmaxf(y, 0.f);
                r2 += __builtin_amdgcn_exp2f(-fabsf(y));
            }
    if (diag) {
#pragma unroll
        for (int mf = 0; mf < 2; ++mf)
#pragma unroll
            for (int nf = 0; nf < 2; ++nf)
#pragma unroll
                for (int q = 0; q < 16; ++q) {
                    int i_loc = wm * 64 + mf * 32 + (q & 3) + 8 * (q >> 2) + 4 * h;
                    int j_loc = wn * 64 + nf * 32 + l31;   // panel1: cols 0..127
                    if (i_loc == j_loc) {
                        float y  = acc[mf][nf][q];
                        float u  = -(y + 2.f * b2);
                        float ey = __builtin_amdgcn_exp2f(-fabsf(y));
                        float eu = __builtin_amdgcn_exp2f(-fabsf(u));
                        ld += (LN2 * fmaxf(u, 0.f) + eu) - (LN2 * fmaxf(y, 0.f) + ey);
                    }
                }
    }

    // ================= panel 2 =================
#pragma unroll
    for (int mf = 0; mf < 2; ++mf)
#pragma unroll
        for (int nf = 0; nf < 2; ++nf)
#pragma unroll
            for (int q = 0; q < 16; ++q) acc[mf][nf][q] = -b2;

    asm volatile("s_waitcnt vmcnt(0)" ::: "memory");   // B2 landed
    __builtin_amdgcn_s_barrier();
    asm volatile("" ::: "memory");

#pragma unroll
    for (int s = 0; s < 4; ++s) {
        int cb = s * 4 + h * 2;
        int8v aF0 = read_frag256(As, wm * 64 + l31, cb);
        int8v aF1 = read_frag256(As, wm * 64 + 32 + l31, cb);
        int8v bF0 = read_frag256(Bs2, wn * 64 + l31, cb);
        int8v bF1 = read_frag256(Bs2, wn * 64 + 32 + l31, cb);
        acc[0][0] = __builtin_amdgcn_mfma_scale_f32_32x32x64_f8f6f4(
            aF0, bF0, acc[0][0], 0, 0, 0, 0x7F7F7F7F, 0, 0x7F7F7F7F);
        acc[0][1] = __builtin_amdgcn_mfma_scale_f32_32x32x64_f8f6f4(
            aF0, bF1, acc[0][1], 0, 0, 0, 0x7F7F7F7F, 0, 0x7F7F7F7F);
        acc[1][0] = __builtin_amdgcn_mfma_scale_f32_32x32x64_f8f6f4(
            aF1, bF0, acc[1][0], 0, 0, 0, 0x7F7F7F7F, 0, 0x7F7F7F7F);
        acc[1][1] = __builtin_amdgcn_mfma_scale_f32_32x32x64_f8f6f4(
            aF1, bF1, acc[1][1], 0, 0, 0, 0x7F7F7F7F, 0, 0x7F7F7F7F);
    }

    // epilogue 2
#pragma unroll
    for (int mf = 0; mf < 2; ++mf)
#pragma unroll
        for (int nf = 0; nf < 2; ++nf)
#pragma unroll
            for (int q = 0; q < 16; ++q) {
                float y = acc[mf][nf][q];
                r1 += fmaxf(y, 0.f);
                r2 += __builtin_amdgcn_exp2f(-fabsf(y));
            }
    if (diag) {
#pragma unroll
        for (int mf = 0; mf < 2; ++mf)
#pragma unroll
            for (int nf = 0; nf < 2; ++nf)
#pragma unroll
                for (int q = 0; q < 16; ++q) {
                    int i_loc = wm * 64 + mf * 32 + (q & 3) + 8 * (q >> 2) + 4 * h;
                    int j_loc = 128 + wn * 64 + nf * 32 + l31;  // panel2 cols
                    if (i_loc == j_loc) {
                        float y  = acc[mf][nf][q];
                        float u  = -(y + 2.f * b2);
                        float ey = __builtin_amdgcn_exp2f(-fabsf(y));
                        float eu = __builtin_amdgcn_exp2f(-fabsf(u));
                        ld += (LN2 * fmaxf(u, 0.f) + eu) - (LN2 * fmaxf(y, 0.f) + ey);
                    }
                }
    }

    float v = fmaf(LN2, r1, r2) + ld;   // nats

    // wave reduce then block reduce
#pragma unroll
    for (int off = 32; off; off >>= 1)
        v += __shfl_down(v, off);
    if (lane == 0) wsum[wid] = v;
    __syncthreads();
    if (tid == 0) {
        float t = 0.f;
#pragma unroll
        for (int w = 0; w < 8; ++w) t += wsum[w];
        atomicAdd(out, t * (1.0f / ((float)Nn * (float)Nn)));
    }
}

extern "C" void kernel_launch(void* const* d_in, const int* in_sizes, int n_in,
                              void* d_out, int out_size, void* d_ws, size_t ws_size,
                              hipStream_t stream) {
    const float* za   = (const float*)d_in[0];
    const float* zb   = (const float*)d_in[1];
    const float* bias = (const float*)d_in[2];

    unsigned char* wa = (unsigned char*)d_ws;
    unsigned char* wb = wa + (size_t)Nn * Dd;

    // zero the output accumulator (harness does not re-poison between replays)
    hipMemsetAsync(d_out, 0, sizeof(float), stream);

    // fp32 -> fp8 pre-pass (A pre-scaled by log2e)
    cvt_kernel<<<dim3(Nn * Dd / 2048), 256, 0, stream>>>(
        (const float4*)za, (const float4*)zb, (int2*)wa, (int2*)wb);

    // fused GEMM + loss: grid 64 x 64 = 4096 blocks
    siglip_kernel<<<dim3(4096), 512, 0, stream>>>(wa, wb, bias, (float*)d_out);
}

// Round 13
// 924.032 us; speedup vs baseline: 1.0068x; 1.0068x over previous
//
#include <hip/hip_runtime.h>
#include <hip/hip_bf16.h>

#define Nn 16384
#define Dd 256
#define L2E 1.4426950408889634f
#define LN2 0.6931471805599453f

typedef __attribute__((ext_vector_type(8))) int int8v;
typedef __attribute__((ext_vector_type(16))) float f32x16;

__device__ inline void gload_lds16(const void* g, void* l) {
    __builtin_amdgcn_global_load_lds(
        (const __attribute__((address_space(1))) void*)g,
        (__attribute__((address_space(3))) void*)l, 16, 0, 0);
}

// fp32 -> fp8 e4m3 (HW RNE). A pre-scaled by log2e: epilogue softplus works in
// exp2/log2 domain with no per-element muls.
__global__ __launch_bounds__(256) void cvt_kernel(
        const float4* __restrict__ a, const float4* __restrict__ b,
        int2* __restrict__ oa, int2* __restrict__ ob) {
    int i = blockIdx.x * 256 + threadIdx.x;
    float4 a0 = a[2 * i], a1 = a[2 * i + 1];
    float4 b0 = b[2 * i], b1 = b[2 * i + 1];
    int alo = __builtin_amdgcn_cvt_pk_fp8_f32(a0.x * L2E, a0.y * L2E, 0, false);
    alo     = __builtin_amdgcn_cvt_pk_fp8_f32(a0.z * L2E, a0.w * L2E, alo, true);
    int ahi = __builtin_amdgcn_cvt_pk_fp8_f32(a1.x * L2E, a1.y * L2E, 0, false);
    ahi     = __builtin_amdgcn_cvt_pk_fp8_f32(a1.z * L2E, a1.w * L2E, ahi, true);
    int blo = __builtin_amdgcn_cvt_pk_fp8_f32(b0.x, b0.y, 0, false);
    blo     = __builtin_amdgcn_cvt_pk_fp8_f32(b0.z, b0.w, blo, true);
    int bhi = __builtin_amdgcn_cvt_pk_fp8_f32(b1.x, b1.y, 0, false);
    bhi     = __builtin_amdgcn_cvt_pk_fp8_f32(b1.z, b1.w, bhi, true);
    oa[i] = make_int2(alo, ahi);
    ob[i] = make_int2(blo, bhi);
}

// 2x ds_read_b128 of one lane's 32 contiguous K-bytes from a [rows][256B]
// full-K LDS tile, XOR-deswizzled (16 chunks/row, chunk ^= row&15).
// Measured ZERO bank conflicts (R8-R12).
__device__ inline int8v read_frag256(const unsigned char* base, int rr, int cb) {
    int x = rr & 15;
    int4 lo = *(const int4*)&base[rr * 256 + ((cb ^ x) * 16)];
    int4 hi = *(const int4*)&base[rr * 256 + (((cb + 1) ^ x) * 16)];
    int8v r;
    r[0] = lo.x; r[1] = lo.y; r[2] = lo.z; r[3] = lo.w;
    r[4] = hi.x; r[5] = hi.y; r[6] = hi.z; r[7] = hi.w;
    return r;
}

// Fused MX-fp8 GEMM (sim' = log2e * za.zb^T, unit e8m0 scales) + siglip loss.
// Two-panel straight-line pipeline (R12) + sched_barrier(0) phase fences:
// R12 spilled because panel-2's register-only acc init hoisted above
// epilogue-1 (rule #18: "memory" clobbers don't order register-only ops),
// making BOTH acc generations live -> 128 AGPR -> unified spill. The fences
// pin: MFMA1 -> epilogue1 -> acc2 init -> MFMA2 -> epilogue2, so exactly ONE
// acc generation is ever live (R10's proven 116-VGPR shape).
__global__ __launch_bounds__(512, 2) void siglip_kernel(
        const unsigned char* __restrict__ ga,   // za*log2e fp8 [16384][256]
        const unsigned char* __restrict__ gb,   // zb fp8 [16384][256]
        const float* __restrict__ bp,           // bias scalar
        float* __restrict__ out) {
    __shared__ unsigned char As[256 * 256];    // 64 KB, full-K A tile
    __shared__ unsigned char Bs1[128 * 256];   // 32 KB, full-K B panel 1
    __shared__ unsigned char Bs2[128 * 256];   // 32 KB, full-K B panel 2
    __shared__ float wsum[8];

    const int tid  = threadIdx.x;
    const int lane = tid & 63;
    const int wid  = tid >> 6;
    const int wm   = wid >> 1;     // 0..3 -> 64-row slice of the 256-row tile
    const int wn   = wid & 1;      // 0..1 -> 64-col slice of a 128-col panel
    const int l31  = lane & 31;
    const int h    = lane >> 5;

    // XCD-chunked swizzle + 8x8 supertile (grid 4096 = 8 XCD x 512).
    const int bid = blockIdx.x;
    const int nid = (bid & 7) * 512 + (bid >> 3);
    const int sc  = nid >> 6, sl = nid & 63;
    const int by  = (sc >> 3) * 8 + (sl >> 3);   // 0..63 (M/256)
    const int bx  = (sc & 7) * 8 + (sl & 7);     // 0..63 (N/256)
    const size_t rowA0 = (size_t)by * 256;
    const size_t rowB0 = (size_t)bx * 256;

    const float b2 = bp[0] * L2E;

    // ---- issue ALL staging upfront: A(8/thr), B1(4/thr), B2(4/thr) ----
    // source chunk pre-swizzled ((c&15)^(row&15)) -> conflict-free reads.
#pragma unroll
    for (int p = 0; p < 8; ++p) {
        int c = p * 512 + tid; int row = c >> 4;
        int scl = (c & 15) ^ (row & 15);
        gload_lds16(&ga[(rowA0 + row) * Dd + scl * 16], &As[c * 16]);
    }
#pragma unroll
    for (int p = 0; p < 4; ++p) {
        int c = p * 512 + tid; int row = c >> 4;
        int scl = (c & 15) ^ (row & 15);
        gload_lds16(&gb[(rowB0 + row) * Dd + scl * 16], &Bs1[c * 16]);
    }
#pragma unroll
    for (int p = 0; p < 4; ++p) {
        int c = p * 512 + tid; int row = c >> 4;
        int scl = (c & 15) ^ (row & 15);
        gload_lds16(&gb[(rowB0 + 128 + row) * Dd + scl * 16], &Bs2[c * 16]);
    }

    float r1 = 0.f, r2 = 0.f, ld = 0.f;
    const int diag = (bx == by);

    // ================= panel 1 =================
    f32x16 acc[2][2];
#pragma unroll
    for (int mf = 0; mf < 2; ++mf)
#pragma unroll
        for (int nf = 0; nf < 2; ++nf)
#pragma unroll
            for (int q = 0; q < 16; ++q) acc[mf][nf][q] = -b2;

    // wait A+B1 landed; B2's 4 loads stay in flight (hidden under panel 1)
    asm volatile("s_waitcnt vmcnt(4)" ::: "memory");
    __builtin_amdgcn_s_barrier();
    __builtin_amdgcn_sched_barrier(0);

#pragma unroll
    for (int s = 0; s < 4; ++s) {
        int cb = s * 4 + h * 2;
        int8v aF0 = read_frag256(As, wm * 64 + l31, cb);
        int8v aF1 = read_frag256(As, wm * 64 + 32 + l31, cb);
        int8v bF0 = read_frag256(Bs1, wn * 64 + l31, cb);
        int8v bF1 = read_frag256(Bs1, wn * 64 + 32 + l31, cb);
        acc[0][0] = __builtin_amdgcn_mfma_scale_f32_32x32x64_f8f6f4(
            aF0, bF0, acc[0][0], 0, 0, 0, 0x7F7F7F7F, 0, 0x7F7F7F7F);
        acc[0][1] = __builtin_amdgcn_mfma_scale_f32_32x32x64_f8f6f4(
            aF0, bF1, acc[0][1], 0, 0, 0, 0x7F7F7F7F, 0, 0x7F7F7F7F);
        acc[1][0] = __builtin_amdgcn_mfma_scale_f32_32x32x64_f8f6f4(
            aF1, bF0, acc[1][0], 0, 0, 0, 0x7F7F7F7F, 0, 0x7F7F7F7F);
        acc[1][1] = __builtin_amdgcn_mfma_scale_f32_32x32x64_f8f6f4(
            aF1, bF1, acc[1][1], 0, 0, 0, 0x7F7F7F7F, 0, 0x7F7F7F7F);
    }

    // FENCE: MFMA1 fully before epilogue1 (no panel-2 code may move up here)
    __builtin_amdgcn_sched_barrier(0);

    // epilogue 1 (pure VALU/trans; B2 lands underneath)
#pragma unroll
    for (int mf = 0; mf < 2; ++mf)
#pragma unroll
        for (int nf = 0; nf < 2; ++nf)
#pragma unroll
            for (int q = 0; q < 16; ++q) {
                float y = acc[mf][nf][q];
                r1 += fmaxf(y, 0.f);
                r2 += __builtin_amdgcn_exp2f(-fabsf(y));
            }
    if (diag) {
#pragma unroll
        for (int mf = 0; mf < 2; ++mf)
#pragma unroll
            for (int nf = 0; nf < 2; ++nf)
#pragma unroll
                for (int q = 0; q < 16; ++q) {
                    int i_loc = wm * 64 + mf * 32 + (q & 3) + 8 * (q >> 2) + 4 * h;
                    int j_loc = wn * 64 + nf * 32 + l31;   // panel1: cols 0..127
                    if (i_loc == j_loc) {
                        float y  = acc[mf][nf][q];
                        float u  = -(y + 2.f * b2);
                        float ey = __builtin_amdgcn_exp2f(-fabsf(y));
                        float eu = __builtin_amdgcn_exp2f(-fabsf(u));
                        ld += (LN2 * fmaxf(u, 0.f) + eu) - (LN2 * fmaxf(y, 0.f) + ey);
                    }
                }
    }

    // FENCE: acc1 is dead HERE. Panel-2's acc init may only start now ->
    // exactly one acc generation live at any time (the R12 spill killer).
    __builtin_amdgcn_sched_barrier(0);

    // ================= panel 2 =================
#pragma unroll
    for (int mf = 0; mf < 2; ++mf)
#pragma unroll
        for (int nf = 0; nf < 2; ++nf)
#pragma unroll
            for (int q = 0; q < 16; ++q) acc[mf][nf][q] = -b2;

    asm volatile("s_waitcnt vmcnt(0)" ::: "memory");   // B2 landed
    __builtin_amdgcn_s_barrier();
    __builtin_amdgcn_sched_barrier(0);

#pragma unroll
    for (int s = 0; s < 4; ++s) {
        int cb = s * 4 + h * 2;
        int8v aF0 = read_frag256(As, wm * 64 + l31, cb);
        int8v aF1 = read_frag256(As, wm * 64 + 32 + l31, cb);
        int8v bF0 = read_frag256(Bs2, wn * 64 + l31, cb);
        int8v bF1 = read_frag256(Bs2, wn * 64 + 32 + l31, cb);
        acc[0][0] = __builtin_amdgcn_mfma_scale_f32_32x32x64_f8f6f4(
            aF0, bF0, acc[0][0], 0, 0, 0, 0x7F7F7F7F, 0, 0x7F7F7F7F);
        acc[0][1] = __builtin_amdgcn_mfma_scale_f32_32x32x64_f8f6f4(
            aF0, bF1, acc[0][1], 0, 0, 0, 0x7F7F7F7F, 0, 0x7F7F7F7F);
        acc[1][0] = __builtin_amdgcn_mfma_scale_f32_32x32x64_f8f6f4(
            aF1, bF0, acc[1][0], 0, 0, 0, 0x7F7F7F7F, 0, 0x7F7F7F7F);
        acc[1][1] = __builtin_amdgcn_mfma_scale_f32_32x32x64_f8f6f4(
            aF1, bF1, acc[1][1], 0, 0, 0, 0x7F7F7F7F, 0, 0x7F7F7F7F);
    }

    // FENCE: MFMA2 fully before epilogue2
    __builtin_amdgcn_sched_barrier(0);

    // epilogue 2
#pragma unroll
    for (int mf = 0; mf < 2; ++mf)
#pragma unroll
        for (int nf = 0; nf < 2; ++nf)
#pragma unroll
            for (int q = 0; q < 16; ++q) {
                float y = acc[mf][nf][q];
                r1 += fmaxf(y, 0.f);
                r2 += __builtin_amdgcn_exp2f(-fabsf(y));
            }
    if (diag) {
#pragma unroll
        for (int mf = 0; mf < 2; ++mf)
#pragma unroll
            for (int nf = 0; nf < 2; ++nf)
#pragma unroll
                for (int q = 0; q < 16; ++q) {
                    int i_loc = wm * 64 + mf * 32 + (q & 3) + 8 * (q >> 2) + 4 * h;
                    int j_loc = 128 + wn * 64 + nf * 32 + l31;  // panel2 cols
                    if (i_loc == j_loc) {
                        float y  = acc[mf][nf][q];
                        float u  = -(y + 2.f * b2);
                        float ey = __builtin_amdgcn_exp2f(-fabsf(y));
                        float eu = __builtin_amdgcn_exp2f(-fabsf(u));
                        ld += (LN2 * fmaxf(u, 0.f) + eu) - (LN2 * fmaxf(y, 0.f) + ey);
                    }
                }
    }

    float v = fmaf(LN2, r1, r2) + ld;   // nats

    // wave reduce then block reduce
#pragma unroll
    for (int off = 32; off; off >>= 1)
        v += __shfl_down(v, off);
    if (lane == 0) wsum[wid] = v;
    __syncthreads();
    if (tid == 0) {
        float t = 0.f;
#pragma unroll
        for (int w = 0; w < 8; ++w) t += wsum[w];
        atomicAdd(out, t * (1.0f / ((float)Nn * (float)Nn)));
    }
}

extern "C" void kernel_launch(void* const* d_in, const int* in_sizes, int n_in,
                              void* d_out, int out_size, void* d_ws, size_t ws_size,
                              hipStream_t stream) {
    const float* za   = (const float*)d_in[0];
    const float* zb   = (const float*)d_in[1];
    const float* bias = (const float*)d_in[2];

    unsigned char* wa = (unsigned char*)d_ws;
    unsigned char* wb = wa + (size_t)Nn * Dd;

    // zero the output accumulator (harness does not re-poison between replays)
    hipMemsetAsync(d_out, 0, sizeof(float), stream);

    // fp32 -> fp8 pre-pass (A pre-scaled by log2e)
    cvt_kernel<<<dim3(Nn * Dd / 2048), 256, 0, stream>>>(
        (const float4*)za, (const float4*)zb, (int2*)wa, (int2*)wb);

    // fused GEMM + loss: grid 64 x 64 = 4096 blocks
    siglip_kernel<<<dim3(4096), 512, 0, stream>>>(wa, wb, bias, (float*)d_out);
}

// Round 14
// 828.584 us; speedup vs baseline: 1.1227x; 1.1152x over previous
//
#include <hip/hip_runtime.h>
#include <hip/hip_bf16.h>

#define Nn 16384
#define Dd 256
#define L2E 1.4426950408889634f
#define LN2 0.6931471805599453f

typedef __attribute__((ext_vector_type(8))) int int8v;
typedef __attribute__((ext_vector_type(16))) float f32x16;

__device__ inline void gload_lds16(const void* g, void* l) {
    __builtin_amdgcn_global_load_lds(
        (const __attribute__((address_space(1))) void*)g,
        (__attribute__((address_space(3))) void*)l, 16, 0, 0);
}

// fp32 -> fp8 e4m3 (HW RNE). A pre-scaled by log2e: epilogue softplus works in
// exp2/log2 domain with no per-element muls.
__global__ __launch_bounds__(256) void cvt_kernel(
        const float4* __restrict__ a, const float4* __restrict__ b,
        int2* __restrict__ oa, int2* __restrict__ ob) {
    int i = blockIdx.x * 256 + threadIdx.x;
    float4 a0 = a[2 * i], a1 = a[2 * i + 1];
    float4 b0 = b[2 * i], b1 = b[2 * i + 1];
    int alo = __builtin_amdgcn_cvt_pk_fp8_f32(a0.x * L2E, a0.y * L2E, 0, false);
    alo     = __builtin_amdgcn_cvt_pk_fp8_f32(a0.z * L2E, a0.w * L2E, alo, true);
    int ahi = __builtin_amdgcn_cvt_pk_fp8_f32(a1.x * L2E, a1.y * L2E, 0, false);
    ahi     = __builtin_amdgcn_cvt_pk_fp8_f32(a1.z * L2E, a1.w * L2E, ahi, true);
    int blo = __builtin_amdgcn_cvt_pk_fp8_f32(b0.x, b0.y, 0, false);
    blo     = __builtin_amdgcn_cvt_pk_fp8_f32(b0.z, b0.w, blo, true);
    int bhi = __builtin_amdgcn_cvt_pk_fp8_f32(b1.x, b1.y, 0, false);
    bhi     = __builtin_amdgcn_cvt_pk_fp8_f32(b1.z, b1.w, bhi, true);
    oa[i] = make_int2(alo, ahi);
    ob[i] = make_int2(blo, bhi);
}

// 2x ds_read_b128 of one lane's 32 contiguous K-bytes from a [rows][256B]
// full-K LDS tile, XOR-deswizzled (16 chunks/row, chunk ^= row&15).
// Measured ZERO bank conflicts (R8-R13).
__device__ inline int8v read_frag256(const unsigned char* base, int rr, int cb) {
    int x = rr & 15;
    int4 lo = *(const int4*)&base[rr * 256 + ((cb ^ x) * 16)];
    int4 hi = *(const int4*)&base[rr * 256 + (((cb + 1) ^ x) * 16)];
    int8v r;
    r[0] = lo.x; r[1] = lo.y; r[2] = lo.z; r[3] = lo.w;
    r[4] = hi.x; r[5] = hi.y; r[6] = hi.z; r[7] = hi.w;
    return r;
}

// Pin the 4 accumulator fragments into AGPRs. Every spilling round reported
// VGPR_Count = exactly half the unified cap -> the allocator splits arch/AGPR
// at the midpoint and spills when the ARCH side overflows. Forcing acc into
// the AGPR half (64-128 AGPRs, which R10 left mostly idle) keeps arch demand
// at the frag/addressing level (~110 < 128).
#define PIN_ACC(A)                                                            \
    asm volatile("" : "+a"((A)[0][0]), "+a"((A)[0][1]),                       \
                      "+a"((A)[1][0]), "+a"((A)[1][1]))

// Fused MX-fp8 GEMM (sim' = log2e * za.zb^T, unit e8m0 scales) + siglip loss.
// Two-panel straight-line pipeline: stage A(64KB)+B1(32KB)+B2(32KB) upfront,
// vmcnt(4) -> MFMA1 + epilogue1 (B2 in flight underneath) -> vmcnt(0) ->
// MFMA2 + epilogue2. A staged once for 256 output cols. sched_barrier fences
// pin phase order; PIN_ACC pins accumulators to AGPRs (the R12/R13 spill was
// an ARCH-side overflow, not an ordering problem).
__global__ __launch_bounds__(512, 2) void siglip_kernel(
        const unsigned char* __restrict__ ga,   // za*log2e fp8 [16384][256]
        const unsigned char* __restrict__ gb,   // zb fp8 [16384][256]
        const float* __restrict__ bp,           // bias scalar
        float* __restrict__ out) {
    __shared__ unsigned char As[256 * 256];    // 64 KB, full-K A tile
    __shared__ unsigned char Bs1[128 * 256];   // 32 KB, full-K B panel 1
    __shared__ unsigned char Bs2[128 * 256];   // 32 KB, full-K B panel 2
    __shared__ float wsum[8];

    const int tid  = threadIdx.x;
    const int lane = tid & 63;
    const int wid  = tid >> 6;
    const int wm   = wid >> 1;     // 0..3 -> 64-row slice of the 256-row tile
    const int wn   = wid & 1;      // 0..1 -> 64-col slice of a 128-col panel
    const int l31  = lane & 31;
    const int h    = lane >> 5;

    // XCD-chunked swizzle + 8x8 supertile (grid 4096 = 8 XCD x 512).
    const int bid = blockIdx.x;
    const int nid = (bid & 7) * 512 + (bid >> 3);
    const int sc  = nid >> 6, sl = nid & 63;
    const int by  = (sc >> 3) * 8 + (sl >> 3);   // 0..63 (M/256)
    const int bx  = (sc & 7) * 8 + (sl & 7);     // 0..63 (N/256)
    const size_t rowA0 = (size_t)by * 256;
    const size_t rowB0 = (size_t)bx * 256;

    const float b2 = bp[0] * L2E;

    // ---- issue ALL staging upfront: A(8/thr), B1(4/thr), B2(4/thr) ----
    // source chunk pre-swizzled ((c&15)^(row&15)) -> conflict-free reads.
#pragma unroll
    for (int p = 0; p < 8; ++p) {
        int c = p * 512 + tid; int row = c >> 4;
        int scl = (c & 15) ^ (row & 15);
        gload_lds16(&ga[(rowA0 + row) * Dd + scl * 16], &As[c * 16]);
    }
#pragma unroll
    for (int p = 0; p < 4; ++p) {
        int c = p * 512 + tid; int row = c >> 4;
        int scl = (c & 15) ^ (row & 15);
        gload_lds16(&gb[(rowB0 + row) * Dd + scl * 16], &Bs1[c * 16]);
    }
#pragma unroll
    for (int p = 0; p < 4; ++p) {
        int c = p * 512 + tid; int row = c >> 4;
        int scl = (c & 15) ^ (row & 15);
        gload_lds16(&gb[(rowB0 + 128 + row) * Dd + scl * 16], &Bs2[c * 16]);
    }

    float r1 = 0.f, r2 = 0.f, ld = 0.f;
    const int diag = (bx == by);

    // ================= panel 1 =================
    f32x16 acc[2][2];
#pragma unroll
    for (int mf = 0; mf < 2; ++mf)
#pragma unroll
        for (int nf = 0; nf < 2; ++nf)
#pragma unroll
            for (int q = 0; q < 16; ++q) acc[mf][nf][q] = -b2;
    PIN_ACC(acc);   // init lives in AGPRs

    // wait A+B1 landed; B2's 4 loads stay in flight (hidden under panel 1)
    asm volatile("s_waitcnt vmcnt(4)" ::: "memory");
    __builtin_amdgcn_s_barrier();
    __builtin_amdgcn_sched_barrier(0);

#pragma unroll
    for (int s = 0; s < 4; ++s) {
        int cb = s * 4 + h * 2;
        int8v aF0 = read_frag256(As, wm * 64 + l31, cb);
        int8v aF1 = read_frag256(As, wm * 64 + 32 + l31, cb);
        int8v bF0 = read_frag256(Bs1, wn * 64 + l31, cb);
        int8v bF1 = read_frag256(Bs1, wn * 64 + 32 + l31, cb);
        acc[0][0] = __builtin_amdgcn_mfma_scale_f32_32x32x64_f8f6f4(
            aF0, bF0, acc[0][0], 0, 0, 0, 0x7F7F7F7F, 0, 0x7F7F7F7F);
        acc[0][1] = __builtin_amdgcn_mfma_scale_f32_32x32x64_f8f6f4(
            aF0, bF1, acc[0][1], 0, 0, 0, 0x7F7F7F7F, 0, 0x7F7F7F7F);
        acc[1][0] = __builtin_amdgcn_mfma_scale_f32_32x32x64_f8f6f4(
            aF1, bF0, acc[1][0], 0, 0, 0, 0x7F7F7F7F, 0, 0x7F7F7F7F);
        acc[1][1] = __builtin_amdgcn_mfma_scale_f32_32x32x64_f8f6f4(
            aF1, bF1, acc[1][1], 0, 0, 0, 0x7F7F7F7F, 0, 0x7F7F7F7F);
    }
    PIN_ACC(acc);   // results stay in AGPRs
    __builtin_amdgcn_sched_barrier(0);

    // epilogue 1 (pure VALU/trans; B2 lands underneath)
#pragma unroll
    for (int mf = 0; mf < 2; ++mf)
#pragma unroll
        for (int nf = 0; nf < 2; ++nf)
#pragma unroll
            for (int q = 0; q < 16; ++q) {
                float y = acc[mf][nf][q];
                r1 += fmaxf(y, 0.f);
                r2 += __builtin_amdgcn_exp2f(-fabsf(y));
            }
    if (diag) {
#pragma unroll
        for (int mf = 0; mf < 2; ++mf)
#pragma unroll
            for (int nf = 0; nf < 2; ++nf)
#pragma unroll
                for (int q = 0; q < 16; ++q) {
                    int i_loc = wm * 64 + mf * 32 + (q & 3) + 8 * (q >> 2) + 4 * h;
                    int j_loc = wn * 64 + nf * 32 + l31;   // panel1: cols 0..127
                    if (i_loc == j_loc) {
                        float y  = acc[mf][nf][q];
                        float u  = -(y + 2.f * b2);
                        float ey = __builtin_amdgcn_exp2f(-fabsf(y));
                        float eu = __builtin_amdgcn_exp2f(-fabsf(u));
                        ld += (LN2 * fmaxf(u, 0.f) + eu) - (LN2 * fmaxf(y, 0.f) + ey);
                    }
                }
    }

    // FENCE: acc gen-1 dead here; gen-2 init may only start now.
    __builtin_amdgcn_sched_barrier(0);

    // ================= panel 2 =================
#pragma unroll
    for (int mf = 0; mf < 2; ++mf)
#pragma unroll
        for (int nf = 0; nf < 2; ++nf)
#pragma unroll
            for (int q = 0; q < 16; ++q) acc[mf][nf][q] = -b2;
    PIN_ACC(acc);

    asm volatile("s_waitcnt vmcnt(0)" ::: "memory");   // B2 landed
    __builtin_amdgcn_s_barrier();
    __builtin_amdgcn_sched_barrier(0);

#pragma unroll
    for (int s = 0; s < 4; ++s) {
        int cb = s * 4 + h * 2;
        int8v aF0 = read_frag256(As, wm * 64 + l31, cb);
        int8v aF1 = read_frag256(As, wm * 64 + 32 + l31, cb);
        int8v bF0 = read_frag256(Bs2, wn * 64 + l31, cb);
        int8v bF1 = read_frag256(Bs2, wn * 64 + 32 + l31, cb);
        acc[0][0] = __builtin_amdgcn_mfma_scale_f32_32x32x64_f8f6f4(
            aF0, bF0, acc[0][0], 0, 0, 0, 0x7F7F7F7F, 0, 0x7F7F7F7F);
        acc[0][1] = __builtin_amdgcn_mfma_scale_f32_32x32x64_f8f6f4(
            aF0, bF1, acc[0][1], 0, 0, 0, 0x7F7F7F7F, 0, 0x7F7F7F7F);
        acc[1][0] = __builtin_amdgcn_mfma_scale_f32_32x32x64_f8f6f4(
            aF1, bF0, acc[1][0], 0, 0, 0, 0x7F7F7F7F, 0, 0x7F7F7F7F);
        acc[1][1] = __builtin_amdgcn_mfma_scale_f32_32x32x64_f8f6f4(
            aF1, bF1, acc[1][1], 0, 0, 0, 0x7F7F7F7F, 0, 0x7F7F7F7F);
    }
    PIN_ACC(acc);
    __builtin_amdgcn_sched_barrier(0);

    // epilogue 2
#pragma unroll
    for (int mf = 0; mf < 2; ++mf)
#pragma unroll
        for (int nf = 0; nf < 2; ++nf)
#pragma unroll
            for (int q = 0; q < 16; ++q) {
                float y = acc[mf][nf][q];
                r1 += fmaxf(y, 0.f);
                r2 += __builtin_amdgcn_exp2f(-fabsf(y));
            }
    if (diag) {
#pragma unroll
        for (int mf = 0; mf < 2; ++mf)
#pragma unroll
            for (int nf = 0; nf < 2; ++nf)
#pragma unroll
                for (int q = 0; q < 16; ++q) {
                    int i_loc = wm * 64 + mf * 32 + (q & 3) + 8 * (q >> 2) + 4 * h;
                    int j_loc = 128 + wn * 64 + nf * 32 + l31;  // panel2 cols
                    if (i_loc == j_loc) {
                        float y  = acc[mf][nf][q];
                        float u  = -(y + 2.f * b2);
                        float ey = __builtin_amdgcn_exp2f(-fabsf(y));
                        float eu = __builtin_amdgcn_exp2f(-fabsf(u));
                        ld += (LN2 * fmaxf(u, 0.f) + eu) - (LN2 * fmaxf(y, 0.f) + ey);
                    }
                }
    }

    float v = fmaf(LN2, r1, r2) + ld;   // nats

    // wave reduce then block reduce
#pragma unroll
    for (int off = 32; off; off >>= 1)
        v += __shfl_down(v, off);
    if (lane == 0) wsum[wid] = v;
    __syncthreads();
    if (tid == 0) {
        float t = 0.f;
#pragma unroll
        for (int w = 0; w < 8; ++w) t += wsum[w];
        atomicAdd(out, t * (1.0f / ((float)Nn * (float)Nn)));
    }
}

extern "C" void kernel_launch(void* const* d_in, const int* in_sizes, int n_in,
                              void* d_out, int out_size, void* d_ws, size_t ws_size,
                              hipStream_t stream) {
    const float* za   = (const float*)d_in[0];
    const float* zb   = (const float*)d_in[1];
    const float* bias = (const float*)d_in[2];

    unsigned char* wa = (unsigned char*)d_ws;
    unsigned char* wb = wa + (size_t)Nn * Dd;

    // zero the output accumulator (harness does not re-poison between replays)
    hipMemsetAsync(d_out, 0, sizeof(float), stream);

    // fp32 -> fp8 pre-pass (A pre-scaled by log2e)
    cvt_kernel<<<dim3(Nn * Dd / 2048), 256, 0, stream>>>(
        (const float4*)za, (const float4*)zb, (int2*)wa, (int2*)wb);

    // fused GEMM + loss: grid 64 x 64 = 4096 blocks
    siglip_kernel<<<dim3(4096), 512, 0, stream>>>(wa, wb, bias, (float*)d_out);
}

// Round 15
// 144.440 us; speedup vs baseline: 6.4406x; 5.7365x over previous
//
#include <hip/hip_runtime.h>
#include <hip/hip_bf16.h>

#define Nn 16384
#define Dd 256
#define L2E 1.4426950408889634f
#define LN2 0.6931471805599453f

typedef __attribute__((ext_vector_type(8))) int int8v;
typedef __attribute__((ext_vector_type(16))) float f32x16;
typedef __attribute__((ext_vector_type(2))) float f32x2;

__device__ inline void gload_lds16(const void* g, void* l) {
    __builtin_amdgcn_global_load_lds(
        (const __attribute__((address_space(1))) void*)g,
        (__attribute__((address_space(3))) void*)l, 16, 0, 0);
}

// fp32 -> fp8 e4m3 (HW RNE). A pre-scaled by log2e: epilogue softplus works in
// exp2/log2 domain with no per-element muls.
__global__ __launch_bounds__(256) void cvt_kernel(
        const float4* __restrict__ a, const float4* __restrict__ b,
        int2* __restrict__ oa, int2* __restrict__ ob) {
    int i = blockIdx.x * 256 + threadIdx.x;
    float4 a0 = a[2 * i], a1 = a[2 * i + 1];
    float4 b0 = b[2 * i], b1 = b[2 * i + 1];
    int alo = __builtin_amdgcn_cvt_pk_fp8_f32(a0.x * L2E, a0.y * L2E, 0, false);
    alo     = __builtin_amdgcn_cvt_pk_fp8_f32(a0.z * L2E, a0.w * L2E, alo, true);
    int ahi = __builtin_amdgcn_cvt_pk_fp8_f32(a1.x * L2E, a1.y * L2E, 0, false);
    ahi     = __builtin_amdgcn_cvt_pk_fp8_f32(a1.z * L2E, a1.w * L2E, ahi, true);
    int blo = __builtin_amdgcn_cvt_pk_fp8_f32(b0.x, b0.y, 0, false);
    blo     = __builtin_amdgcn_cvt_pk_fp8_f32(b0.z, b0.w, blo, true);
    int bhi = __builtin_amdgcn_cvt_pk_fp8_f32(b1.x, b1.y, 0, false);
    bhi     = __builtin_amdgcn_cvt_pk_fp8_f32(b1.z, b1.w, bhi, true);
    oa[i] = make_int2(alo, ahi);
    ob[i] = make_int2(blo, bhi);
}

// 2x ds_read_b128 of one lane's 32 contiguous K-bytes from a [rows][256B]
// full-K LDS tile, XOR-deswizzled (16 chunks/row, chunk ^= row&15).
// Measured ZERO bank conflicts (R8-R14): any 8 consecutive lanes have
// distinct low-3 slot bits -> conflict-free per b128 phase.
__device__ inline int8v read_frag256(const unsigned char* base, int rr, int cb) {
    int x = rr & 15;
    int4 lo = *(const int4*)&base[rr * 256 + ((cb ^ x) * 16)];
    int4 hi = *(const int4*)&base[rr * 256 + (((cb + 1) ^ x) * 16)];
    int8v r;
    r[0] = lo.x; r[1] = lo.y; r[2] = lo.z; r[3] = lo.w;
    r[4] = hi.x; r[5] = hi.y; r[6] = hi.z; r[7] = hi.w;
    return r;
}

// Fused MX-fp8 GEMM (sim' = log2e * za.zb^T, unit e8m0 scales) + siglip loss.
// R10 keeper structure (straight-line, single acc generation — every multi-
// phase variant R8/R9/R12/R13/R14 spilled the unified file): tile 256x128,
// full K=256 staged once (96KB LDS, conflict-free XOR-16 layout), one
// vmcnt(0)+barrier, 16 MFMAs, register epilogue. 512 thr = 8 waves (4Mx2N),
// wave tile 64x64 -> acc[2][2] f32x16 (116 VGPR + 64 AGPR, no spill).
// R15 delta: packed-f32 epilogue — Σmax(y,0) = ½(Σy + Σ|y|) lets the three
// running sums use v_pk_add_f32 on aligned acc pairs (~40% epilogue VALU cut).
__global__ __launch_bounds__(512, 2) void siglip_kernel(
        const unsigned char* __restrict__ ga,   // za*log2e fp8 [16384][256]
        const unsigned char* __restrict__ gb,   // zb fp8 [16384][256]
        const float* __restrict__ bp,           // bias scalar
        float* __restrict__ out) {
    __shared__ unsigned char As[256 * 256];   // 64 KB, full-K A tile
    __shared__ unsigned char Bs[128 * 256];   // 32 KB, full-K B tile
    __shared__ float wsum[8];

    const int tid  = threadIdx.x;
    const int lane = tid & 63;
    const int wid  = tid >> 6;
    const int wm   = wid >> 1;     // 0..3 -> 64-row slice of the 256-row tile
    const int wn   = wid & 1;      // 0..1 -> 64-col slice of the 128-col tile
    const int l31  = lane & 31;
    const int h    = lane >> 5;

    // XCD-chunked swizzle + 8x8 supertile (grid 8192 = 8 XCD x 1024).
    const int bid = blockIdx.x;
    const int nid = (bid & 7) * 1024 + (bid >> 3);
    const int sc  = nid >> 6, sl = nid & 63;
    const int by  = (sc & 7) * 8 + (sl >> 3);    // 0..63  (M/256)
    const int bx  = (sc >> 3) * 8 + (sl & 7);    // 0..127 (N/128)
    const size_t rowA0 = (size_t)by * 256;
    const size_t rowB0 = (size_t)bx * 128;

    const float b2 = bp[0] * L2E;

    // ---- stage the whole block slice ONCE: 12 loads/thread ----
    // source chunk pre-swizzled ((c&15)^(row&15)) so read_frag256's XOR'd
    // ds_read_b128 deswizzles correctly (bank-conflict-free, proven).
#pragma unroll
    for (int p = 0; p < 8; ++p) {
        int c = p * 512 + tid; int row = c >> 4;
        int scl = (c & 15) ^ (row & 15);
        gload_lds16(&ga[(rowA0 + row) * Dd + scl * 16], &As[c * 16]);
    }
#pragma unroll
    for (int p = 0; p < 4; ++p) {
        int c = p * 512 + tid; int row = c >> 4;
        int scl = (c & 15) ^ (row & 15);
        gload_lds16(&gb[(rowB0 + row) * Dd + scl * 16], &Bs[c * 16]);
    }

    // bias folded into MFMA C operand: acc ends as y = s' - b2
    f32x16 acc[2][2];
#pragma unroll
    for (int mf = 0; mf < 2; ++mf)
#pragma unroll
        for (int nf = 0; nf < 2; ++nf)
#pragma unroll
            for (int q = 0; q < 16; ++q) acc[mf][nf][q] = -b2;

    asm volatile("s_waitcnt vmcnt(0)" ::: "memory");
    __builtin_amdgcn_s_barrier();
    asm volatile("" ::: "memory");

    // ---- K = 256 in 4 s-steps of 64B, straight-line, 16 MFMAs/wave ----
#pragma unroll
    for (int s = 0; s < 4; ++s) {
        int cb = s * 4 + h * 2;
        int8v aF0 = read_frag256(As, wm * 64 + l31, cb);
        int8v aF1 = read_frag256(As, wm * 64 + 32 + l31, cb);
        int8v bF0 = read_frag256(Bs, wn * 64 + l31, cb);
        int8v bF1 = read_frag256(Bs, wn * 64 + 32 + l31, cb);
        acc[0][0] = __builtin_amdgcn_mfma_scale_f32_32x32x64_f8f6f4(
            aF0, bF0, acc[0][0], 0, 0, 0, 0x7F7F7F7F, 0, 0x7F7F7F7F);
        acc[0][1] = __builtin_amdgcn_mfma_scale_f32_32x32x64_f8f6f4(
            aF0, bF1, acc[0][1], 0, 0, 0, 0x7F7F7F7F, 0, 0x7F7F7F7F);
        acc[1][0] = __builtin_amdgcn_mfma_scale_f32_32x32x64_f8f6f4(
            aF1, bF0, acc[1][0], 0, 0, 0, 0x7F7F7F7F, 0, 0x7F7F7F7F);
        acc[1][1] = __builtin_amdgcn_mfma_scale_f32_32x32x64_f8f6f4(
            aF1, bF1, acc[1][1], 0, 0, 0, 0x7F7F7F7F, 0, 0x7F7F7F7F);
    }
    // no trailing barrier: waves desync into the VALU/trans epilogue.

    // ---- epilogue (packed): nats/elem = ln2*max(y,0) + ln(1+2^-|y|)
    //   ~= ln2*max(y,0) + 2^-|y|  (drop e^2/2: R10-proven, absmax 0.031)
    //   Σmax(y,0) = 0.5*(Σy + Σ|y|) -> three pk_add-able running sums.
    f32x2 sy = {0.f, 0.f}, sa = {0.f, 0.f}, se = {0.f, 0.f};
#pragma unroll
    for (int mf = 0; mf < 2; ++mf)
#pragma unroll
        for (int nf = 0; nf < 2; ++nf)
#pragma unroll
            for (int q = 0; q < 16; q += 2) {
                float y0 = acc[mf][nf][q];
                float y1 = acc[mf][nf][q + 1];
                f32x2 yv = {y0, y1};
                f32x2 av = {fabsf(y0), fabsf(y1)};
                sy += yv;                   // v_pk_add_f32
                sa += av;                   // v_pk_add_f32
                f32x2 ev = {__builtin_amdgcn_exp2f(-av[0]),
                            __builtin_amdgcn_exp2f(-av[1])};
                se += ev;                   // v_pk_add_f32
            }
    float ld = 0.f;

    // Diagonal correction where this block's row-range meets its col-range.
    if ((bx >> 1) == by) {
#pragma unroll
        for (int mf = 0; mf < 2; ++mf)
#pragma unroll
            for (int nf = 0; nf < 2; ++nf)
#pragma unroll
                for (int q = 0; q < 16; ++q) {
                    int i_loc = wm * 64 + mf * 32 + (q & 3) + 8 * (q >> 2) + 4 * h;
                    int j_loc = (bx & 1) * 128 + wn * 64 + nf * 32 + l31;
                    if (i_loc == j_loc) {
                        float y  = acc[mf][nf][q];
                        float u  = -(y + 2.f * b2);
                        float ey = __builtin_amdgcn_exp2f(-fabsf(y));
                        float eu = __builtin_amdgcn_exp2f(-fabsf(u));
                        float off = LN2 * fmaxf(y, 0.f) + ey;
                        float dg  = LN2 * fmaxf(u, 0.f) + eu;
                        ld += dg - off;
                    }
                }
    }

    // v = ln2 * 0.5*(Σy + Σ|y|) + Σe + diag
    float v = fmaf(LN2 * 0.5f, (sy[0] + sy[1]) + (sa[0] + sa[1]),
                   (se[0] + se[1]) + ld);

    // wave reduce then block reduce
#pragma unroll
    for (int off = 32; off; off >>= 1)
        v += __shfl_down(v, off);
    if (lane == 0) wsum[wid] = v;
    __syncthreads();
    if (tid == 0) {
        float t = 0.f;
#pragma unroll
        for (int w = 0; w < 8; ++w) t += wsum[w];
        atomicAdd(out, t * (1.0f / ((float)Nn * (float)Nn)));
    }
}

extern "C" void kernel_launch(void* const* d_in, const int* in_sizes, int n_in,
                              void* d_out, int out_size, void* d_ws, size_t ws_size,
                              hipStream_t stream) {
    const float* za   = (const float*)d_in[0];
    const float* zb   = (const float*)d_in[1];
    const float* bias = (const float*)d_in[2];

    unsigned char* wa = (unsigned char*)d_ws;
    unsigned char* wb = wa + (size_t)Nn * Dd;

    // zero the output accumulator (harness does not re-poison between replays)
    hipMemsetAsync(d_out, 0, sizeof(float), stream);

    // fp32 -> fp8 pre-pass (A pre-scaled by log2e)
    cvt_kernel<<<dim3(Nn * Dd / 2048), 256, 0, stream>>>(
        (const float4*)za, (const float4*)zb, (int2*)wa, (int2*)wb);

    // fused GEMM + loss: grid 64 x 128 = 8192 blocks
    siglip_kernel<<<dim3(8192), 512, 0, stream>>>(wa, wb, bias, (float*)d_out);
}